// Round 23
// baseline (81.222 us; speedup 1.0000x reference)
//
#include <hip/hip_runtime.h>

typedef unsigned char uchar;
typedef unsigned long long ull;
typedef __attribute__((ext_vector_type(2))) unsigned long long ullx2;
typedef __attribute__((ext_vector_type(4))) float floatx4;
typedef __attribute__((ext_vector_type(4))) unsigned int uintx4;
typedef __attribute__((ext_vector_type(8))) int intx8;

#define NB_IMG 18496      // 136 y * 2 p * 68 xh pixel slots per batch image
#define WHALF 9216        // bytes per eval per weight half (9*4*32*8)
#define AREG 16352        // A-tile LDS bytes (680 px * 24 B + 32 guard)
#define NBLK 3904         // main-kernel block count (122 per batch)
#define NPART4 3904       // float4 count of partials (NBLK*4 floats)
#define USCALE 0x7F7F7F7F // E8M0 unit scales in every byte

// ---- fp32 -> fp8 e4m3 (OCP), RNE ----
__device__ __forceinline__ uchar f2e4(float x) {
    float a = fabsf(x);
    unsigned s = (__float_as_uint(x) >> 24) & 0x80u;
    if (a >= 448.f) return (uchar)(s | 0x7E);
    if (a < 0.015625f) {
        int m = (int)rintf(a * 512.f);
        return (uchar)(s | (unsigned)m);
    }
    unsigned u = __float_as_uint(a);
    unsigned r = u + 0x7FFFFu + ((u >> 20) & 1u);
    unsigned e8 = (r >> 23) - 120u;
    return (uchar)(s | (e8 << 3) | ((r >> 20) & 7u));
}

// 16-lane (DPP row) sum: all lanes end with the row total
__device__ __forceinline__ float row16sum(float v) {
    v += __int_as_float(__builtin_amdgcn_update_dpp(0, __float_as_int(v), 0x128, 0xf, 0xf, false));
    v += __int_as_float(__builtin_amdgcn_update_dpp(0, __float_as_int(v), 0x124, 0xf, 0xf, false));
    v += __int_as_float(__builtin_amdgcn_update_dpp(0, __float_as_int(v), 0x122, 0xf, 0xf, false));
    v += __int_as_float(__builtin_amdgcn_update_dpp(0, __float_as_int(v), 0x121, 0xf, 0xf, false));
    return v;
}

// bundle four 8-B K=32 fragments into one K=128 operand (register renaming only)
__device__ __forceinline__ intx8 pack8(ull a, ull b, ull c, ull d) {
    intx8 v;
    v[0] = (int)(unsigned)a; v[1] = (int)(a >> 32);
    v[2] = (int)(unsigned)b; v[3] = (int)(b >> 32);
    v[4] = (int)(unsigned)c; v[5] = (int)(c >> 32);
    v[6] = (int)(unsigned)d; v[7] = (int)(d >> 32);
    return v;
}

__device__ __forceinline__ void eval_geom(int e, int& sy0, int& sx0, int& cch, int& s_idx) {
    if (e < 3) { sy0 = 0; sx0 = 0; cch = e; s_idx = -1; }
    else {
        int u = e - 3; int s = (u % 9) / 3; cch = u % 3; s_idx = s;
        sy0 = (s == 1) ? 0 : 1;
        sx0 = (s == 2) ? 0 : 1;
    }
}

__device__ __forceinline__ bool tap_active(int e, int ci, int dy, int dx,
                                           int sy0, int sx0, int cch, int s_idx) {
    if (ci >= 3) return true;
    int py = (sy0 + dy - 1) & 1;
    int px = (sx0 + dx - 1) & 1;
    if (e < 3) return (py == 0 && px == 0) && (ci < cch);
    if (py == 0 && px == 0) return true;
    int sp = (py == 1 && px == 1) ? 0 : ((py == 0 && px == 1) ? 1 : 2);
    return (sp < s_idx) || (sp == s_idx && ci < cch);
}

// ---- merged prepass: cvt (blocks 0..577, float4-vectorized) + wpk (578..766) ----
__global__ __launch_bounds__(256) void prep_kernel(
    const float* __restrict__ value, const float* __restrict__ dp,
    const float* __restrict__ W1,
    uchar* __restrict__ imgbf, uchar* __restrict__ wbfA, uchar* __restrict__ wbfB)
{
    const int bid = blockIdx.x;
    if (bid < 578) {
        const int t = bid * 256 + threadIdx.x;     // 147,968 = 32*136*34 exactly
        const int b = t / 4624;                    // 136*34
        const int r = t - b * 4624;
        const int y = r / 34;
        const int xh4 = r - y * 34;
        const int yi = y - 4;
        uchar* dst = imgbf + ((size_t)b * NB_IMG + (size_t)y * 136) * 32;

        if ((unsigned)yi < 128u && xh4 >= 1 && xh4 <= 32) {
            const int xi0 = 4 * xh4 - 4;
            const float* vb = value + (size_t)b * 3 * 16384 + yi * 128 + xi0;
            const float* pb = dp + (size_t)b * 16 * 16384 + yi * 128 + xi0;
            floatx4 ch[19];
            #pragma unroll
            for (int i = 0; i < 3; ++i)  ch[i]     = *(const floatx4*)(vb + i * 16384);
            #pragma unroll
            for (int i = 0; i < 16; ++i) ch[3 + i] = *(const floatx4*)(pb + i * 16384);
            #pragma unroll
            for (int e = 0; e < 4; ++e) {
                unsigned d[8];
                #pragma unroll
                for (int i = 0; i < 8; ++i) d[i] = 0;
                #pragma unroll
                for (int ci = 0; ci < 19; ++ci)
                    d[ci >> 2] |= (unsigned)f2e4(ch[ci][e]) << ((ci & 3) * 8);
                uchar* ds = dst + (((e & 1) * 68) + 2 * xh4 + (e >> 1)) * 32;
                uintx4 v0, v1;
                v0[0] = d[0]; v0[1] = d[1]; v0[2] = d[2]; v0[3] = d[3];
                v1[0] = d[4]; v1[1] = d[5]; v1[2] = d[6]; v1[3] = d[7];
                *(uintx4*)ds = v0;
                *(uintx4*)(ds + 16) = v1;
            }
        } else {
            uintx4 z; z[0] = 0; z[1] = 0; z[2] = 0; z[3] = 0;
            #pragma unroll
            for (int e = 0; e < 4; ++e) {
                uchar* ds = dst + (((e & 1) * 68) + 2 * xh4 + (e >> 1)) * 32;
                *(uintx4*)ds = z;
                *(uintx4*)(ds + 16) = z;
            }
        }
    } else {
        // masked fp8 weights, fragment-major; cols 0..31 -> wbfA, 32..63 -> wbfB
        const int q = bid - 578;                   // 0..188
        const int e = q / 9, tap = q % 9;
        const int g = threadIdx.x >> 6, n = threadIdx.x & 63;
        int sy0, sx0, cch, s_idx;
        eval_geom(e, sy0, sx0, cch, s_idx);
        const int dy = tap / 3, dx = tap % 3;
        const float* wrow = W1 + ((size_t)e * 64 + n) * 171;
        ull v = 0;
        #pragma unroll
        for (int qq = 0; qq < 8; ++qq) {
            const int ci = g * 8 + qq;
            float w = 0.f;
            if (ci < 19 && tap_active(e, ci, dy, dx, sy0, sx0, cch, s_idx))
                w = wrow[ci * 9 + tap];
            v |= (ull)f2e4(w) << (qq * 8);
        }
        if (n < 32) *(ull*)&wbfA[(size_t)e * WHALF + ((tap * 4 + g) * 32 + n) * 8] = v;
        else        *(ull*)&wbfB[(size_t)e * WHALF + ((tap * 4 + g) * 32 + (n - 32)) * 8] = v;
    }
}

// ---- one parity class per block: 3 evals share A-tile. W-halves of evals 0,1
// staged in LDS (18.4 KB); eval 2 reads its W-half straight from global (L2-hot).
// LDS total 34.8 KB -> 4 blocks/CU. Single barrier; 3 unrolled eval-tasks/wave.
template<int SY0, int SX0, int RSH, int OWSH, int TXH, int TY>
__device__ __forceinline__ void run_class(
    int e0, int b, int oy0, int ox0, int tid, int bid,
    uchar* Alds, uchar* Wlds,
    const uchar* __restrict__ imgbf, const uchar* __restrict__ wbfA,
    const uchar* __restrict__ wbfB, const float* __restrict__ value,
    const float* __restrict__ b1, const float* __restrict__ W2,
    const float* __restrict__ b2, float* __restrict__ partials)
{
    constexpr int TPIX = TY * 2 * TXH;
    constexpr int OW = 1 << OWSH;
    const int lane = tid & 63, w = tid >> 6;
    const int l15 = lane & 15, l4 = lane >> 4;
    const int wfb = l4 * 256 + l15 * 8;

    // ---- T14: issue evals 0,1 W-half loads early (1152 ullx2 chunks) ----
    ullx2 swv[5];
    const uchar* wsrc = wbfB + (size_t)e0 * WHALF;
    #pragma unroll
    for (int i = 0; i < 5; ++i) {
        const int cc = tid + i * 256;
        if (cc < 1152) swv[i] = *(const ullx2*)(wsrc + (size_t)cc * 16);
    }

    // ---- stage A-tile (fp8, 24 B/px); W-load latency spans this ----
    const int yb = 2 * oy0 - 1, xb = 2 * ox0 - 2;
    const uchar* img_b = imgbf + (size_t)b * ((size_t)NB_IMG * 32);
    #pragma unroll
    for (int i = 0; i < (TPIX + 255) / 256; ++i) {
        const int px = tid + i * 256;
        if (px < TPIX) {
            const int typ = px / TXH;
            const int xh = px - typ * TXH;
            const int yl = yb + (typ >> 1);
            const int xl = xb + 2 * xh + (typ & 1);
            int yi = (yl << RSH) + 4; yi = yi < 0 ? 0 : (yi > 135 ? 135 : yi);
            int xi = (xl << RSH) + 4; xi = xi < 0 ? 0 : (xi > 135 ? 135 : xi);
            const uchar* src = img_b + (size_t)(yi * 136 + (xi & 1) * 68 + (xi >> 1)) * 32;
            ullx2 v01 = *(const ullx2*)src;
            ull v2 = *(const ull*)(src + 16);
            uchar* dst = Alds + px * 24;
            *(ull*)dst = v01[0];
            *(ull*)(dst + 8) = v01[1];
            *(ull*)(dst + 16) = v2;
        }
    }
    if (tid < 4) *(ull*)(Alds + TPIX * 24 + tid * 8) = 0ull;   // l4=3 overread guard
    #pragma unroll
    for (int i = 0; i < 5; ++i) {
        const int cc = tid + i * 256;
        if (cc < 1152) *(ullx2*)(Wlds + (size_t)cc * 16) = swv[i];
    }
    __syncthreads();                     // the ONLY barrier

    int abase[2];
    #pragma unroll
    for (int a = 0; a < 2; ++a) {
        const int row = w * 32 + a * 16 + l15;
        const int oy = row >> OWSH, ox = row & (OW - 1);
        abase[a] = ((SY0 + 2 * oy) * 2 * TXH + ox) * 24 + l4 * 8;
    }

    float lpsum = 0.f;

    #pragma unroll
    for (int c = 0; c < 3; ++c) {        // 3 independent eval-tasks, no barriers
        const int e = e0 + c;
        const uchar* wA = wbfA + (size_t)e * WHALF;
        // evals 0,1: LDS; eval 2: global (L2-resident, per-lane addresses)
        const uchar* Wb = (c < 2) ? (const uchar*)(Wlds + (size_t)c * WHALF)
                                  : (wbfB + (size_t)e * WHALF);

        ull breg[9][2];
        #pragma unroll
        for (int tap = 0; tap < 9; ++tap) {
            breg[tap][0] = *(const ull*)(wA + tap * 1024 + wfb);
            breg[tap][1] = *(const ull*)(wA + tap * 1024 + wfb + 128);
        }
        float b1c[4], w2c[4];
        #pragma unroll
        for (int nb = 0; nb < 4; ++nb) {
            b1c[nb] = b1[e * 64 + nb * 16 + l15];
            w2c[nb] = W2[e * 64 + nb * 16 + l15];
        }
        const float bias2 = b2[e];

        floatx4 acc[2][4];
        #pragma unroll
        for (int a = 0; a < 2; ++a)
            #pragma unroll
            for (int nb = 0; nb < 4; ++nb)
                acc[a][nb] = (floatx4){0.f, 0.f, 0.f, 0.f};

        __builtin_amdgcn_s_setprio(1);
        // ---- taps 0..7 via two K=128 MX MFMAs per (a,nb), unit scales ----
        #pragma unroll
        for (int tg = 0; tg < 2; ++tg) {
            ull av0[4], av1[4];
            #pragma unroll
            for (int j = 0; j < 4; ++j) {
                const int tap = tg * 4 + j;
                const int dy = tap / 3, dx = tap % 3;
                const int vv = SX0 + dx + 1;
                const int D = (2 * dy + (vv & 1)) * TXH + (vv >> 1);   // compile-time
                av0[j] = *(const ull*)(Alds + abase[0] + D * 24);
                av1[j] = *(const ull*)(Alds + abase[1] + D * 24);
            }
            const intx8 A80 = pack8(av0[0], av0[1], av0[2], av0[3]);
            const intx8 A81 = pack8(av1[0], av1[1], av1[2], av1[3]);
            const intx8 B0 = pack8(breg[tg*4+0][0], breg[tg*4+1][0], breg[tg*4+2][0], breg[tg*4+3][0]);
            const intx8 B1 = pack8(breg[tg*4+0][1], breg[tg*4+1][1], breg[tg*4+2][1], breg[tg*4+3][1]);
            const uchar* wbl = Wb + wfb + tg * 4096;
            const intx8 B2 = pack8(*(const ull*)(wbl),        *(const ull*)(wbl + 1024),
                                   *(const ull*)(wbl + 2048), *(const ull*)(wbl + 3072));
            const intx8 B3 = pack8(*(const ull*)(wbl + 128),  *(const ull*)(wbl + 1152),
                                   *(const ull*)(wbl + 2176), *(const ull*)(wbl + 3200));
            acc[0][0] = __builtin_amdgcn_mfma_scale_f32_16x16x128_f8f6f4(A80, B0, acc[0][0], 0, 0, 0, USCALE, 0, USCALE);
            acc[1][0] = __builtin_amdgcn_mfma_scale_f32_16x16x128_f8f6f4(A81, B0, acc[1][0], 0, 0, 0, USCALE, 0, USCALE);
            acc[0][1] = __builtin_amdgcn_mfma_scale_f32_16x16x128_f8f6f4(A80, B1, acc[0][1], 0, 0, 0, USCALE, 0, USCALE);
            acc[1][1] = __builtin_amdgcn_mfma_scale_f32_16x16x128_f8f6f4(A81, B1, acc[1][1], 0, 0, 0, USCALE, 0, USCALE);
            acc[0][2] = __builtin_amdgcn_mfma_scale_f32_16x16x128_f8f6f4(A80, B2, acc[0][2], 0, 0, 0, USCALE, 0, USCALE);
            acc[1][2] = __builtin_amdgcn_mfma_scale_f32_16x16x128_f8f6f4(A81, B2, acc[1][2], 0, 0, 0, USCALE, 0, USCALE);
            acc[0][3] = __builtin_amdgcn_mfma_scale_f32_16x16x128_f8f6f4(A80, B3, acc[0][3], 0, 0, 0, USCALE, 0, USCALE);
            acc[1][3] = __builtin_amdgcn_mfma_scale_f32_16x16x128_f8f6f4(A81, B3, acc[1][3], 0, 0, 0, USCALE, 0, USCALE);
        }
        // ---- tap 8: plain K=32 fp8 MFMA (same 16x16 C layout) ----
        {
            const int dy = 2, dx = 2;
            const int vv = SX0 + dx + 1;
            const int D = (2 * dy + (vv & 1)) * TXH + (vv >> 1);
            const ull a0 = *(const ull*)(Alds + abase[0] + D * 24);
            const ull a1 = *(const ull*)(Alds + abase[1] + D * 24);
            const ull bv2 = *(const ull*)(Wb + wfb + 8 * 1024);
            const ull bv3 = *(const ull*)(Wb + wfb + 8 * 1024 + 128);
            acc[0][0] = __builtin_amdgcn_mfma_f32_16x16x32_fp8_fp8((long)a0, (long)breg[8][0], acc[0][0], 0, 0, 0);
            acc[1][0] = __builtin_amdgcn_mfma_f32_16x16x32_fp8_fp8((long)a1, (long)breg[8][0], acc[1][0], 0, 0, 0);
            acc[0][1] = __builtin_amdgcn_mfma_f32_16x16x32_fp8_fp8((long)a0, (long)breg[8][1], acc[0][1], 0, 0, 0);
            acc[1][1] = __builtin_amdgcn_mfma_f32_16x16x32_fp8_fp8((long)a1, (long)breg[8][1], acc[1][1], 0, 0, 0);
            acc[0][2] = __builtin_amdgcn_mfma_f32_16x16x32_fp8_fp8((long)a0, (long)bv2, acc[0][2], 0, 0, 0);
            acc[1][2] = __builtin_amdgcn_mfma_f32_16x16x32_fp8_fp8((long)a1, (long)bv2, acc[1][2], 0, 0, 0);
            acc[0][3] = __builtin_amdgcn_mfma_f32_16x16x32_fp8_fp8((long)a0, (long)bv3, acc[0][3], 0, 0, 0);
            acc[1][3] = __builtin_amdgcn_mfma_f32_16x16x32_fp8_fp8((long)a1, (long)bv3, acc[1][3], 0, 0, 0);
        }
        __builtin_amdgcn_s_setprio(0);

        // ---- epilogue: 8 row-sums; 32 lanes each finish one row ----
        float zv[8];
        #pragma unroll
        for (int a = 0; a < 2; ++a)
            #pragma unroll
            for (int j = 0; j < 4; ++j) {
                float part = 0.f;
                #pragma unroll
                for (int nb = 0; nb < 4; ++nb)
                    part += w2c[nb] * fmaxf(acc[a][nb][j] + b1c[nb], 0.f);
                zv[a * 4 + j] = row16sum(part);
            }
        if (l15 < 8) {
            const float u0 = (l15 & 1) ? zv[1] : zv[0];
            const float u1 = (l15 & 1) ? zv[3] : zv[2];
            const float u2 = (l15 & 1) ? zv[5] : zv[4];
            const float u3 = (l15 & 1) ? zv[7] : zv[6];
            const float p0 = (l15 & 2) ? u1 : u0;
            const float p1 = (l15 & 2) ? u3 : u2;
            const float zs = ((l15 & 4) ? p1 : p0) + bias2;
            const int row = w * 32 + ((l15 >> 2) << 4) + (l4 << 2) + (l15 & 3);
            const int oyj = oy0 + (row >> OWSH);
            const int oxj = ox0 + (row & (OW - 1));
            const int yj = (SY0 + 2 * oyj) << RSH;
            const int xj = (SX0 + 2 * oxj) << RSH;
            const float xv = value[((size_t)b * 3 + c) * 16384 + yj * 128 + xj];
            const float az = fabsf(zs);
            const float t2 = __builtin_amdgcn_exp2f(-1.442695041f * az);
            const float l1p = 0.69314718056f * __builtin_amdgcn_logf(1.f + t2);
            lpsum += xv * zs + fminf(-zs, 0.f) - l1p;
        }
    }

    // ---- wave reduce -> plain per-wave store (no barrier, no atomics) ----
    lpsum += __shfl_down(lpsum, 32);
    lpsum += __shfl_down(lpsum, 16);
    lpsum += __shfl_down(lpsum, 8);
    lpsum += __shfl_down(lpsum, 4);
    lpsum += __shfl_down(lpsum, 2);
    lpsum += __shfl_down(lpsum, 1);
    if (lane == 0) partials[bid * 4 + w] = lpsum;
}

// ---- main kernel: 3904 blocks (122/batch), 128 rows x 3 evals each ----
__global__ __launch_bounds__(256) void pcnn_all(
    const uchar* __restrict__ imgbf, const uchar* __restrict__ wbfA,
    const uchar* __restrict__ wbfB, const float* __restrict__ value,
    const float* __restrict__ b1, const float* __restrict__ W2,
    const float* __restrict__ b2, float* __restrict__ partials)
{
    __shared__ __align__(16) uchar smem[AREG + 2 * WHALF];   // 34784 B -> 4 blocks/CU
    uchar* Alds = smem;
    uchar* Wlds = smem + AREG;
    const int bid = blockIdx.x, tid = threadIdx.x;

    const int x = bid & 7, r = bid >> 3;
    const int g = r / 122, u = r - g * 122;
    const int b = g * 8 + x;

    if (u < 96) {                       // fine: e 12..20, r=1
        const int s = u >> 5, t = u & 31;
        const int e0 = 12 + s * 3;
        const int oy0 = (t >> 1) * 4, ox0 = (t & 1) * 32;
        if (s == 0)
            run_class<1, 1, 0, 5, 34, 10>(e0, b, oy0, ox0, tid, bid, Alds, Wlds, imgbf, wbfA, wbfB, value, b1, W2, b2, partials);
        else if (s == 1)
            run_class<0, 1, 0, 5, 34, 10>(e0, b, oy0, ox0, tid, bid, Alds, Wlds, imgbf, wbfA, wbfB, value, b1, W2, b2, partials);
        else
            run_class<1, 0, 0, 5, 34, 10>(e0, b, oy0, ox0, tid, bid, Alds, Wlds, imgbf, wbfA, wbfB, value, b1, W2, b2, partials);
    } else if (u < 120) {               // mid: e 3..11, r=2
        const int v = u - 96;
        const int s = v >> 3, t = v & 7;
        const int e0 = 3 + s * 3;
        const int oy0 = t * 4;
        if (s == 0)
            run_class<1, 1, 1, 5, 34, 10>(e0, b, oy0, 0, tid, bid, Alds, Wlds, imgbf, wbfA, wbfB, value, b1, W2, b2, partials);
        else if (s == 1)
            run_class<0, 1, 1, 5, 34, 10>(e0, b, oy0, 0, tid, bid, Alds, Wlds, imgbf, wbfA, wbfB, value, b1, W2, b2, partials);
        else
            run_class<1, 0, 1, 5, 34, 10>(e0, b, oy0, 0, tid, bid, Alds, Wlds, imgbf, wbfA, wbfB, value, b1, W2, b2, partials);
    } else {                            // base: e 0..2, r=4; 8oy x 16ox regions
        const int t = u - 120;
        run_class<0, 0, 2, 4, 18, 18>(0, b, t * 8, 0, tid, bid, Alds, Wlds, imgbf, wbfA, wbfB, value, b1, W2, b2, partials);
    }
}

// ---- final reduce: one block, float4 loads, writes out[0] directly ----
__global__ __launch_bounds__(256) void reduce_kernel(
    const floatx4* __restrict__ p4, float* __restrict__ out)
{
    __shared__ float ws[4];
    const int tid = threadIdx.x;
    float s = 0.f;
    for (int i = tid; i < NPART4; i += 256) {
        floatx4 v = p4[i];
        s += v[0] + v[1] + v[2] + v[3];
    }
    s += __shfl_down(s, 32);
    s += __shfl_down(s, 16);
    s += __shfl_down(s, 8);
    s += __shfl_down(s, 4);
    s += __shfl_down(s, 2);
    s += __shfl_down(s, 1);
    if ((tid & 63) == 0) ws[tid >> 6] = s;
    __syncthreads();
    if (tid == 0) out[0] = ws[0] + ws[1] + ws[2] + ws[3];
}

extern "C" void kernel_launch(void* const* d_in, const int* in_sizes, int n_in,
                              void* d_out, int out_size, void* d_ws, size_t ws_size,
                              hipStream_t stream) {
    const float* value = (const float*)d_in[0];
    const float* dp    = (const float*)d_in[1];
    const float* W1    = (const float*)d_in[2];
    const float* b1    = (const float*)d_in[3];
    const float* W2    = (const float*)d_in[4];
    const float* b2    = (const float*)d_in[5];
    float* out = (float*)d_out;

    uchar* imgbf = (uchar*)d_ws;                                  // 32*18496*32 = 18.94 MB
    uchar* wbfA  = imgbf + (size_t)32 * NB_IMG * 32;              // 21*9216 B
    uchar* wbfB  = wbfA + (size_t)21 * WHALF;                     // 21*9216 B
    float* partials = (float*)(wbfB + (size_t)21 * WHALF);        // 15616 * 4 B

    hipLaunchKernelGGL(prep_kernel, dim3(767), dim3(256), 0, stream,
                       value, dp, W1, imgbf, wbfA, wbfB);
    hipLaunchKernelGGL(pcnn_all, dim3(NBLK), dim3(256), 0, stream,
                       imgbf, wbfA, wbfB, value, b1, W2, b2, partials);
    hipLaunchKernelGGL(reduce_kernel, dim3(1), dim3(256), 0, stream,
                       (const floatx4*)partials, out);
}

// Round 24
// 69.546 us; speedup vs baseline: 1.1679x; 1.1679x over previous
//
#include <hip/hip_runtime.h>

typedef unsigned char uchar;
typedef unsigned long long ull;
typedef __attribute__((ext_vector_type(2))) unsigned long long ullx2;
typedef __attribute__((ext_vector_type(4))) float floatx4;
typedef __attribute__((ext_vector_type(4))) unsigned int uintx4;
typedef __attribute__((ext_vector_type(8))) int intx8;

#define NB_IMG 18496      // 136 y * 2 p * 68 xh pixel slots per batch image
#define WHALF 9216        // bytes per eval per weight half (8192 bundled taps0-7 + 1024 tap8)
#define AREG 16352        // A-tile LDS bytes (680 px * 24 B + 32 guard)
#define NBLK 3904         // main-kernel block count (122 per batch)
#define NPART4 3904       // float4 count of partials (NBLK*4 floats)
#define USCALE 0x7F7F7F7F // E8M0 unit scales in every byte

// ---- fp32 -> fp8 e4m3 (OCP), RNE ----
__device__ __forceinline__ uchar f2e4(float x) {
    float a = fabsf(x);
    unsigned s = (__float_as_uint(x) >> 24) & 0x80u;
    if (a >= 448.f) return (uchar)(s | 0x7E);
    if (a < 0.015625f) {
        int m = (int)rintf(a * 512.f);
        return (uchar)(s | (unsigned)m);
    }
    unsigned u = __float_as_uint(a);
    unsigned r = u + 0x7FFFFu + ((u >> 20) & 1u);
    unsigned e8 = (r >> 23) - 120u;
    return (uchar)(s | (e8 << 3) | ((r >> 20) & 7u));
}

// 16-lane (DPP row) sum: all lanes end with the row total
__device__ __forceinline__ float row16sum(float v) {
    v += __int_as_float(__builtin_amdgcn_update_dpp(0, __float_as_int(v), 0x128, 0xf, 0xf, false));
    v += __int_as_float(__builtin_amdgcn_update_dpp(0, __float_as_int(v), 0x124, 0xf, 0xf, false));
    v += __int_as_float(__builtin_amdgcn_update_dpp(0, __float_as_int(v), 0x122, 0xf, 0xf, false));
    v += __int_as_float(__builtin_amdgcn_update_dpp(0, __float_as_int(v), 0x121, 0xf, 0xf, false));
    return v;
}

// bundle four 8-B K=32 fragments into one K=128 operand (A side only)
__device__ __forceinline__ intx8 pack8(ull a, ull b, ull c, ull d) {
    intx8 v;
    v[0] = (int)(unsigned)a; v[1] = (int)(a >> 32);
    v[2] = (int)(unsigned)b; v[3] = (int)(b >> 32);
    v[4] = (int)(unsigned)c; v[5] = (int)(c >> 32);
    v[6] = (int)(unsigned)d; v[7] = (int)(d >> 32);
    return v;
}

// 32B contiguous K=128 operand load (2 x 16B)
__device__ __forceinline__ intx8 ld8(const uchar* p) {
    uintx4 lo = *(const uintx4*)p;
    uintx4 hi = *(const uintx4*)(p + 16);
    intx8 v;
    v[0] = (int)lo[0]; v[1] = (int)lo[1]; v[2] = (int)lo[2]; v[3] = (int)lo[3];
    v[4] = (int)hi[0]; v[5] = (int)hi[1]; v[6] = (int)hi[2]; v[7] = (int)hi[3];
    return v;
}

__device__ __forceinline__ void eval_geom(int e, int& sy0, int& sx0, int& cch, int& s_idx) {
    if (e < 3) { sy0 = 0; sx0 = 0; cch = e; s_idx = -1; }
    else {
        int u = e - 3; int s = (u % 9) / 3; cch = u % 3; s_idx = s;
        sy0 = (s == 1) ? 0 : 1;
        sx0 = (s == 2) ? 0 : 1;
    }
}

__device__ __forceinline__ bool tap_active(int e, int ci, int dy, int dx,
                                           int sy0, int sx0, int cch, int s_idx) {
    if (ci >= 3) return true;
    int py = (sy0 + dy - 1) & 1;
    int px = (sx0 + dx - 1) & 1;
    if (e < 3) return (py == 0 && px == 0) && (ci < cch);
    if (py == 0 && px == 0) return true;
    int sp = (py == 1 && px == 1) ? 0 : ((py == 0 && px == 1) ? 1 : 2);
    return (sp < s_idx) || (sp == s_idx && ci < cch);
}

// ---- merged prepass: cvt (blocks 0..577, float4-vectorized) + wpk (578..766) ----
// Weight layout per eval (both halves): taps 0..7 BUNDLED for K=128 operands:
//   offset = ((tg*4 + g)*32 + n)*32 + j*8   (tap = tg*4 + j, n = col within half)
// tap 8 appended at +8192: offset = 8192 + (g*32 + n)*8.
__global__ __launch_bounds__(256) void prep_kernel(
    const float* __restrict__ value, const float* __restrict__ dp,
    const float* __restrict__ W1,
    uchar* __restrict__ imgbf, uchar* __restrict__ wbfA, uchar* __restrict__ wbfB)
{
    const int bid = blockIdx.x;
    if (bid < 578) {
        const int t = bid * 256 + threadIdx.x;     // 147,968 = 32*136*34 exactly
        const int b = t / 4624;                    // 136*34
        const int r = t - b * 4624;
        const int y = r / 34;
        const int xh4 = r - y * 34;
        const int yi = y - 4;
        uchar* dst = imgbf + ((size_t)b * NB_IMG + (size_t)y * 136) * 32;

        if ((unsigned)yi < 128u && xh4 >= 1 && xh4 <= 32) {
            const int xi0 = 4 * xh4 - 4;
            const float* vb = value + (size_t)b * 3 * 16384 + yi * 128 + xi0;
            const float* pb = dp + (size_t)b * 16 * 16384 + yi * 128 + xi0;
            floatx4 ch[19];
            #pragma unroll
            for (int i = 0; i < 3; ++i)  ch[i]     = *(const floatx4*)(vb + i * 16384);
            #pragma unroll
            for (int i = 0; i < 16; ++i) ch[3 + i] = *(const floatx4*)(pb + i * 16384);
            #pragma unroll
            for (int e = 0; e < 4; ++e) {
                unsigned d[8];
                #pragma unroll
                for (int i = 0; i < 8; ++i) d[i] = 0;
                #pragma unroll
                for (int ci = 0; ci < 19; ++ci)
                    d[ci >> 2] |= (unsigned)f2e4(ch[ci][e]) << ((ci & 3) * 8);
                uchar* ds = dst + (((e & 1) * 68) + 2 * xh4 + (e >> 1)) * 32;
                uintx4 v0, v1;
                v0[0] = d[0]; v0[1] = d[1]; v0[2] = d[2]; v0[3] = d[3];
                v1[0] = d[4]; v1[1] = d[5]; v1[2] = d[6]; v1[3] = d[7];
                *(uintx4*)ds = v0;
                *(uintx4*)(ds + 16) = v1;
            }
        } else {
            uintx4 z; z[0] = 0; z[1] = 0; z[2] = 0; z[3] = 0;
            #pragma unroll
            for (int e = 0; e < 4; ++e) {
                uchar* ds = dst + (((e & 1) * 68) + 2 * xh4 + (e >> 1)) * 32;
                *(uintx4*)ds = z;
                *(uintx4*)(ds + 16) = z;
            }
        }
    } else {
        // masked fp8 weights; cols 0..31 -> wbfA, 32..63 -> wbfB (bundled layout)
        const int q = bid - 578;                   // 0..188
        const int e = q / 9, tap = q % 9;
        const int g = threadIdx.x >> 6, n = threadIdx.x & 63;
        int sy0, sx0, cch, s_idx;
        eval_geom(e, sy0, sx0, cch, s_idx);
        const int dy = tap / 3, dx = tap % 3;
        const float* wrow = W1 + ((size_t)e * 64 + n) * 171;
        ull v = 0;
        #pragma unroll
        for (int qq = 0; qq < 8; ++qq) {
            const int ci = g * 8 + qq;
            float w = 0.f;
            if (ci < 19 && tap_active(e, ci, dy, dx, sy0, sx0, cch, s_idx))
                w = wrow[ci * 9 + tap];
            v |= (ull)f2e4(w) << (qq * 8);
        }
        const int nh = n & 31;                     // col within half
        uchar* half = (n < 32) ? (wbfA + (size_t)e * WHALF) : (wbfB + (size_t)e * WHALF);
        if (tap < 8) {
            const int tg = tap >> 2, j = tap & 3;
            *(ull*)&half[(((tg * 4 + g) * 32 + nh) * 32) + j * 8] = v;
        } else {
            *(ull*)&half[8192 + (g * 32 + nh) * 8] = v;
        }
    }
}

// ---- one parity class per block: 3 evals share A-tile AND batch-staged W.
// Single barrier; 3 independent eval-tasks per wave. B-operands are 32B
// contiguous (no packing movs); A-operands packed from 4 scattered b64 reads.
template<int SY0, int SX0, int RSH, int OWSH, int TXH, int TY>
__device__ __forceinline__ void run_class(
    int e0, int b, int oy0, int ox0, int tid, int bid,
    uchar* Alds, uchar* Wlds,
    const uchar* __restrict__ imgbf, const uchar* __restrict__ wbfA,
    const uchar* __restrict__ wbfB, const float* __restrict__ value,
    const float* __restrict__ b1, const float* __restrict__ W2,
    const float* __restrict__ b2, float* __restrict__ partials)
{
    constexpr int TPIX = TY * 2 * TXH;
    constexpr int OW = 1 << OWSH;
    const int lane = tid & 63, w = tid >> 6;
    const int l15 = lane & 15, l4 = lane >> 4;

    // ---- T14: issue ALL 3 evals' W-half loads early (27.6 KB contiguous) ----
    ullx2 swv[7];
    const uchar* wsrc = wbfB + (size_t)e0 * WHALF;
    #pragma unroll
    for (int i = 0; i < 7; ++i) {
        const int cc = tid + i * 256;
        if (cc < 1728) swv[i] = *(const ullx2*)(wsrc + (size_t)cc * 16);
    }

    // ---- stage A-tile (fp8, 24 B/px); latency of W loads spans this ----
    const int yb = 2 * oy0 - 1, xb = 2 * ox0 - 2;
    const uchar* img_b = imgbf + (size_t)b * ((size_t)NB_IMG * 32);
    #pragma unroll
    for (int i = 0; i < (TPIX + 255) / 256; ++i) {
        const int px = tid + i * 256;
        if (px < TPIX) {
            const int typ = px / TXH;
            const int xh = px - typ * TXH;
            const int yl = yb + (typ >> 1);
            const int xl = xb + 2 * xh + (typ & 1);
            int yi = (yl << RSH) + 4; yi = yi < 0 ? 0 : (yi > 135 ? 135 : yi);
            int xi = (xl << RSH) + 4; xi = xi < 0 ? 0 : (xi > 135 ? 135 : xi);
            const uchar* src = img_b + (size_t)(yi * 136 + (xi & 1) * 68 + (xi >> 1)) * 32;
            ullx2 v01 = *(const ullx2*)src;
            ull v2 = *(const ull*)(src + 16);
            uchar* dst = Alds + px * 24;
            *(ull*)dst = v01[0];
            *(ull*)(dst + 8) = v01[1];
            *(ull*)(dst + 16) = v2;
        }
    }
    if (tid < 4) *(ull*)(Alds + TPIX * 24 + tid * 8) = 0ull;   // l4=3 overread guard
    #pragma unroll
    for (int i = 0; i < 7; ++i) {
        const int cc = tid + i * 256;
        if (cc < 1728) *(ullx2*)(Wlds + (size_t)cc * 16) = swv[i];
    }
    __syncthreads();                     // the ONLY barrier

    int abase[2];
    #pragma unroll
    for (int a = 0; a < 2; ++a) {
        const int row = w * 32 + a * 16 + l15;
        const int oy = row >> OWSH, ox = row & (OW - 1);
        abase[a] = ((SY0 + 2 * oy) * 2 * TXH + ox) * 24 + l4 * 8;
    }

    float lpsum = 0.f;

    #pragma unroll
    for (int c = 0; c < 3; ++c) {        // 3 independent eval-tasks, no barriers
        const int e = e0 + c;
        const uchar* wA = wbfA + (size_t)e * WHALF;
        const uchar* Wb = Wlds + (size_t)c * WHALF;

        // B0/B1 operands: 32B contiguous loads from global (L2-hot)
        intx8 bregK[2][2];
        #pragma unroll
        for (int tg = 0; tg < 2; ++tg) {
            const uchar* base = wA + ((tg * 4 + l4) * 32 + l15) * 32;
            bregK[tg][0] = ld8(base);
            bregK[tg][1] = ld8(base + 512);        // n = l15+16
        }
        ull breg8[2];
        breg8[0] = *(const ull*)(wA + 8192 + (l4 * 32 + l15) * 8);
        breg8[1] = *(const ull*)(wA + 8192 + (l4 * 32 + l15 + 16) * 8);

        float b1c[4], w2c[4];
        #pragma unroll
        for (int nb = 0; nb < 4; ++nb) {
            b1c[nb] = b1[e * 64 + nb * 16 + l15];
            w2c[nb] = W2[e * 64 + nb * 16 + l15];
        }
        const float bias2 = b2[e];

        floatx4 acc[2][4];
        #pragma unroll
        for (int a = 0; a < 2; ++a)
            #pragma unroll
            for (int nb = 0; nb < 4; ++nb)
                acc[a][nb] = (floatx4){0.f, 0.f, 0.f, 0.f};

        __builtin_amdgcn_s_setprio(1);
        // ---- taps 0..7 via two K=128 MX MFMAs per (a,nb), unit scales ----
        #pragma unroll
        for (int tg = 0; tg < 2; ++tg) {
            ull av0[4], av1[4];
            #pragma unroll
            for (int j = 0; j < 4; ++j) {
                const int tap = tg * 4 + j;
                const int dy = tap / 3, dx = tap % 3;
                const int vv = SX0 + dx + 1;
                const int D = (2 * dy + (vv & 1)) * TXH + (vv >> 1);   // compile-time
                av0[j] = *(const ull*)(Alds + abase[0] + D * 24);
                av1[j] = *(const ull*)(Alds + abase[1] + D * 24);
            }
            const intx8 A80 = pack8(av0[0], av0[1], av0[2], av0[3]);
            const intx8 A81 = pack8(av1[0], av1[1], av1[2], av1[3]);
            // B2/B3: 32B contiguous ds_reads
            const uchar* wbl = Wb + ((tg * 4 + l4) * 32 + l15) * 32;
            const intx8 B2 = ld8(wbl);
            const intx8 B3 = ld8(wbl + 512);
            acc[0][0] = __builtin_amdgcn_mfma_scale_f32_16x16x128_f8f6f4(A80, bregK[tg][0], acc[0][0], 0, 0, 0, USCALE, 0, USCALE);
            acc[1][0] = __builtin_amdgcn_mfma_scale_f32_16x16x128_f8f6f4(A81, bregK[tg][0], acc[1][0], 0, 0, 0, USCALE, 0, USCALE);
            acc[0][1] = __builtin_amdgcn_mfma_scale_f32_16x16x128_f8f6f4(A80, bregK[tg][1], acc[0][1], 0, 0, 0, USCALE, 0, USCALE);
            acc[1][1] = __builtin_amdgcn_mfma_scale_f32_16x16x128_f8f6f4(A81, bregK[tg][1], acc[1][1], 0, 0, 0, USCALE, 0, USCALE);
            acc[0][2] = __builtin_amdgcn_mfma_scale_f32_16x16x128_f8f6f4(A80, B2, acc[0][2], 0, 0, 0, USCALE, 0, USCALE);
            acc[1][2] = __builtin_amdgcn_mfma_scale_f32_16x16x128_f8f6f4(A81, B2, acc[1][2], 0, 0, 0, USCALE, 0, USCALE);
            acc[0][3] = __builtin_amdgcn_mfma_scale_f32_16x16x128_f8f6f4(A80, B3, acc[0][3], 0, 0, 0, USCALE, 0, USCALE);
            acc[1][3] = __builtin_amdgcn_mfma_scale_f32_16x16x128_f8f6f4(A81, B3, acc[1][3], 0, 0, 0, USCALE, 0, USCALE);
        }
        // ---- tap 8: plain K=32 fp8 MFMA ----
        {
            const int dy = 2, dx = 2;
            const int vv = SX0 + dx + 1;
            const int D = (2 * dy + (vv & 1)) * TXH + (vv >> 1);
            const ull a0 = *(const ull*)(Alds + abase[0] + D * 24);
            const ull a1 = *(const ull*)(Alds + abase[1] + D * 24);
            const ull bv2 = *(const ull*)(Wb + 8192 + (l4 * 32 + l15) * 8);
            const ull bv3 = *(const ull*)(Wb + 8192 + (l4 * 32 + l15 + 16) * 8);
            acc[0][0] = __builtin_amdgcn_mfma_f32_16x16x32_fp8_fp8((long)a0, (long)breg8[0], acc[0][0], 0, 0, 0);
            acc[1][0] = __builtin_amdgcn_mfma_f32_16x16x32_fp8_fp8((long)a1, (long)breg8[0], acc[1][0], 0, 0, 0);
            acc[0][1] = __builtin_amdgcn_mfma_f32_16x16x32_fp8_fp8((long)a0, (long)breg8[1], acc[0][1], 0, 0, 0);
            acc[1][1] = __builtin_amdgcn_mfma_f32_16x16x32_fp8_fp8((long)a1, (long)breg8[1], acc[1][1], 0, 0, 0);
            acc[0][2] = __builtin_amdgcn_mfma_f32_16x16x32_fp8_fp8((long)a0, (long)bv2, acc[0][2], 0, 0, 0);
            acc[1][2] = __builtin_amdgcn_mfma_f32_16x16x32_fp8_fp8((long)a1, (long)bv2, acc[1][2], 0, 0, 0);
            acc[0][3] = __builtin_amdgcn_mfma_f32_16x16x32_fp8_fp8((long)a0, (long)bv3, acc[0][3], 0, 0, 0);
            acc[1][3] = __builtin_amdgcn_mfma_f32_16x16x32_fp8_fp8((long)a1, (long)bv3, acc[1][3], 0, 0, 0);
        }
        __builtin_amdgcn_s_setprio(0);

        // ---- epilogue: 8 row-sums; 32 lanes each finish one row ----
        float zv[8];
        #pragma unroll
        for (int a = 0; a < 2; ++a)
            #pragma unroll
            for (int j = 0; j < 4; ++j) {
                float part = 0.f;
                #pragma unroll
                for (int nb = 0; nb < 4; ++nb)
                    part += w2c[nb] * fmaxf(acc[a][nb][j] + b1c[nb], 0.f);
                zv[a * 4 + j] = row16sum(part);
            }
        if (l15 < 8) {
            const float u0 = (l15 & 1) ? zv[1] : zv[0];
            const float u1 = (l15 & 1) ? zv[3] : zv[2];
            const float u2 = (l15 & 1) ? zv[5] : zv[4];
            const float u3 = (l15 & 1) ? zv[7] : zv[6];
            const float p0 = (l15 & 2) ? u1 : u0;
            const float p1 = (l15 & 2) ? u3 : u2;
            const float zs = ((l15 & 4) ? p1 : p0) + bias2;
            const int row = w * 32 + ((l15 >> 2) << 4) + (l4 << 2) + (l15 & 3);
            const int oyj = oy0 + (row >> OWSH);
            const int oxj = ox0 + (row & (OW - 1));
            const int yj = (SY0 + 2 * oyj) << RSH;
            const int xj = (SX0 + 2 * oxj) << RSH;
            const float xv = value[((size_t)b * 3 + c) * 16384 + yj * 128 + xj];
            const float az = fabsf(zs);
            const float t2 = __builtin_amdgcn_exp2f(-1.442695041f * az);
            const float l1p = 0.69314718056f * __builtin_amdgcn_logf(1.f + t2);
            lpsum += xv * zs + fminf(-zs, 0.f) - l1p;
        }
    }

    // ---- wave reduce -> plain per-wave store (no barrier, no atomics) ----
    lpsum += __shfl_down(lpsum, 32);
    lpsum += __shfl_down(lpsum, 16);
    lpsum += __shfl_down(lpsum, 8);
    lpsum += __shfl_down(lpsum, 4);
    lpsum += __shfl_down(lpsum, 2);
    lpsum += __shfl_down(lpsum, 1);
    if (lane == 0) partials[bid * 4 + w] = lpsum;
}

// ---- main kernel: 3904 blocks (122/batch), 128 rows x 3 evals each ----
__global__ __launch_bounds__(256) void pcnn_all(
    const uchar* __restrict__ imgbf, const uchar* __restrict__ wbfA,
    const uchar* __restrict__ wbfB, const float* __restrict__ value,
    const float* __restrict__ b1, const float* __restrict__ W2,
    const float* __restrict__ b2, float* __restrict__ partials)
{
    __shared__ __align__(16) uchar smem[AREG + 3 * WHALF];   // 44000 B -> 3 blocks/CU
    uchar* Alds = smem;
    uchar* Wlds = smem + AREG;
    const int bid = blockIdx.x, tid = threadIdx.x;

    const int x = bid & 7, r = bid >> 3;
    const int g = r / 122, u = r - g * 122;
    const int b = g * 8 + x;

    if (u < 96) {                       // fine: e 12..20, r=1
        const int s = u >> 5, t = u & 31;
        const int e0 = 12 + s * 3;
        const int oy0 = (t >> 1) * 4, ox0 = (t & 1) * 32;
        if (s == 0)
            run_class<1, 1, 0, 5, 34, 10>(e0, b, oy0, ox0, tid, bid, Alds, Wlds, imgbf, wbfA, wbfB, value, b1, W2, b2, partials);
        else if (s == 1)
            run_class<0, 1, 0, 5, 34, 10>(e0, b, oy0, ox0, tid, bid, Alds, Wlds, imgbf, wbfA, wbfB, value, b1, W2, b2, partials);
        else
            run_class<1, 0, 0, 5, 34, 10>(e0, b, oy0, ox0, tid, bid, Alds, Wlds, imgbf, wbfA, wbfB, value, b1, W2, b2, partials);
    } else if (u < 120) {               // mid: e 3..11, r=2
        const int v = u - 96;
        const int s = v >> 3, t = v & 7;
        const int e0 = 3 + s * 3;
        const int oy0 = t * 4;
        if (s == 0)
            run_class<1, 1, 1, 5, 34, 10>(e0, b, oy0, 0, tid, bid, Alds, Wlds, imgbf, wbfA, wbfB, value, b1, W2, b2, partials);
        else if (s == 1)
            run_class<0, 1, 1, 5, 34, 10>(e0, b, oy0, 0, tid, bid, Alds, Wlds, imgbf, wbfA, wbfB, value, b1, W2, b2, partials);
        else
            run_class<1, 0, 1, 5, 34, 10>(e0, b, oy0, 0, tid, bid, Alds, Wlds, imgbf, wbfA, wbfB, value, b1, W2, b2, partials);
    } else {                            // base: e 0..2, r=4; 8oy x 16ox regions
        const int t = u - 120;
        run_class<0, 0, 2, 4, 18, 18>(0, b, t * 8, 0, tid, bid, Alds, Wlds, imgbf, wbfA, wbfB, value, b1, W2, b2, partials);
    }
}

// ---- final reduce: one block, float4 loads, writes out[0] directly ----
__global__ __launch_bounds__(256) void reduce_kernel(
    const floatx4* __restrict__ p4, float* __restrict__ out)
{
    __shared__ float ws[4];
    const int tid = threadIdx.x;
    float s = 0.f;
    for (int i = tid; i < NPART4; i += 256) {
        floatx4 v = p4[i];
        s += v[0] + v[1] + v[2] + v[3];
    }
    s += __shfl_down(s, 32);
    s += __shfl_down(s, 16);
    s += __shfl_down(s, 8);
    s += __shfl_down(s, 4);
    s += __shfl_down(s, 2);
    s += __shfl_down(s, 1);
    if ((tid & 63) == 0) ws[tid >> 6] = s;
    __syncthreads();
    if (tid == 0) out[0] = ws[0] + ws[1] + ws[2] + ws[3];
}

extern "C" void kernel_launch(void* const* d_in, const int* in_sizes, int n_in,
                              void* d_out, int out_size, void* d_ws, size_t ws_size,
                              hipStream_t stream) {
    const float* value = (const float*)d_in[0];
    const float* dp    = (const float*)d_in[1];
    const float* W1    = (const float*)d_in[2];
    const float* b1    = (const float*)d_in[3];
    const float* W2    = (const float*)d_in[4];
    const float* b2    = (const float*)d_in[5];
    float* out = (float*)d_out;

    uchar* imgbf = (uchar*)d_ws;                                  // 32*18496*32 = 18.94 MB
    uchar* wbfA  = imgbf + (size_t)32 * NB_IMG * 32;              // 21*9216 B
    uchar* wbfB  = wbfA + (size_t)21 * WHALF;                     // 21*9216 B
    float* partials = (float*)(wbfB + (size_t)21 * WHALF);        // 15616 * 4 B

    hipLaunchKernelGGL(prep_kernel, dim3(767), dim3(256), 0, stream,
                       value, dp, W1, imgbf, wbfA, wbfB);
    hipLaunchKernelGGL(pcnn_all, dim3(NBLK), dim3(256), 0, stream,
                       imgbf, wbfA, wbfB, value, b1, W2, b2, partials);
    hipLaunchKernelGGL(reduce_kernel, dim3(1), dim3(256), 0, stream,
                       (const floatx4*)partials, out);
}